// Round 3
// baseline (263.087 us; speedup 1.0000x reference)
//
#include <hip/hip_runtime.h>
#include <hip/hip_bf16.h>
#include <stdint.h>

// Problem constants: B=4, T=2048, C=1024, H=16, D=64. Inputs f32, output f32.
#define B_ 4
#define T_ 2048
#define C_ 1024
#define H_ 16
#define D_ 64

typedef __bf16 bf16;
typedef _Float16 f16;
typedef __attribute__((ext_vector_type(8))) __bf16 bf16x8;
typedef __attribute__((ext_vector_type(4))) __bf16 bf16x4;
typedef __attribute__((ext_vector_type(4))) _Float16 f16x4;
typedef __attribute__((ext_vector_type(8))) _Float16 f16x8;
typedef __attribute__((ext_vector_type(4))) float floatx4;

__device__ __forceinline__ floatx4 mfma16(bf16x8 a, bf16x8 b, floatx4 c) {
  return __builtin_amdgcn_mfma_f32_16x16x32_bf16(a, b, c, 0, 0, 0);
}
__device__ __forceinline__ floatx4 mfma_pv(f16x4 a, f16x4 b, floatx4 c) {
  return __builtin_amdgcn_mfma_f32_16x16x16f16(a, b, c, 0, 0, 0);
}

__device__ __forceinline__ void gl_lds16(const void* g, void* l) {
  __builtin_amdgcn_global_load_lds(
      (__attribute__((address_space(1))) uint32_t*)g,
      (__attribute__((address_space(3))) uint32_t*)l, 16, 0, 0);
}

// inline-asm ds_read_b128 with literal offset (derived-waits discipline:
// compiler inserts NO lgkmcnt for these; we place counted waits by hand).
#define DSR(dst, addr, off) \
  asm volatile("ds_read_b128 %0, %1 offset:" #off : "=v"(dst) : "v"(addr))
#define WAITL(n) asm volatile("s_waitcnt lgkmcnt(" #n ")")
#define SBAR() __builtin_amdgcn_sched_barrier(0)

// ---------------- f32 -> bf16 bulk convert ----------------
__global__ __launch_bounds__(256) void cvt_bf16(const float* __restrict__ in,
                                                bf16* __restrict__ out) {
  const size_t i = ((size_t)blockIdx.x * 256 + threadIdx.x) * 4;
  const floatx4 v = *(const floatx4*)(in + i);
  bf16x4 r;
#pragma unroll
  for (int j = 0; j < 4; j++) r[j] = (bf16)v[j];
  *(bf16x4*)(out + i) = r;
}

// ---------------- transpose: in[K][N] f32 -> out[N][K] bf16 ----------------
__global__ __launch_bounds__(256) void transpose_f32(const float* __restrict__ in,
                                                     bf16* __restrict__ out,
                                                     int K, int N) {
  __shared__ bf16 tile[32][33];
  const int n0 = blockIdx.x * 32, k0 = blockIdx.y * 32;
  const int r = threadIdx.x >> 5, c = threadIdx.x & 31;
#pragma unroll
  for (int i = 0; i < 4; i++)
    tile[r + i * 8][c] = (bf16)in[(size_t)(k0 + r + i * 8) * N + n0 + c];
  __syncthreads();
#pragma unroll
  for (int i = 0; i < 4; i++)
    out[(size_t)(n0 + r + i * 8) * K + k0 + c] = tile[c][r + i * 8];
}

// ============================================================================
// QKV GEMM, 256x256 8-phase-style with DERIVED WAITS (T2+T3+T4+T5).
// Retry of r2 with fault-hardening:
//  (1) ds_read base derived via explicit generic->AS(3) addrspacecast (the
//      cast form already proven in gl_lds16) instead of trusting low-32 of
//      the generic pointer -> removes the one plausible DS-address-violation
//      source r2 introduced.
//  (2) one lgkmcnt(0) drain before the main loop so prologue SMEM stragglers
//      can't pollute derived DS counts (DS/SMEM share lgkmcnt, retire OOO).
// Schedule: per phase 0 issue [B0..B3, A0..A3]; lgkmcnt(3) -> A0-row MFMAs;
//   lgkmcnt(2/1/0) -> A1/A2/A3 rows.  Phase 1: A4..A7 (B held in regs).
// Staging: NBUF=4, prefetch 3 tiles, vmcnt(8) per tile boundary (tile t+1
// landed, 8 loads in flight), tail 8->4->0.  Swizzle both-sides, 0-conflict.
// ============================================================================
__global__ __launch_bounds__(512, 2) void gemm_qkv(const bf16* __restrict__ A,
                                                   const bf16* __restrict__ Bt,
                                                   const float* __restrict__ bias,
                                                   bf16* __restrict__ Qb,
                                                   bf16* __restrict__ Kp,
                                                   f16* __restrict__ Vp) {
  extern __shared__ __align__(16) char smem_[];
  const int tid = threadIdx.x;
  const int lane = tid & 63, wv = tid >> 6;  // 8 waves
  const int col = lane & 15, quad = lane >> 4;
  const int wm = wv >> 2, wn = wv & 3;  // 2M x 4N

  // XCD-aware swizzle (384 % 8 == 0 -> chunked form bijective).
  const int id0 = blockIdx.x;
  const int sw = (id0 & 7) * 48 + (id0 >> 3);
  const int bx = sw / 12, by = sw - bx * 12;
  const int m0 = by * 256, n0 = bx * 256;  // m0: channels, n0: tokens

  // ---- staging addresses (per thread; source pre-swizzled) ----
  const int srow = tid >> 2;   // row within 128-row half
  const int schunk = tid & 3;  // 16B chunk within 64B row
  const int sx = ((schunk ^ ((srow >> 1) & 3)) << 3);  // element offset
  const bf16* baseA0 = A + (size_t)(m0 + srow) * 1024 + sx;
  const bf16* baseA1 = baseA0 + (size_t)128 * 1024;
  const bf16* baseB0 = Bt + (size_t)(n0 + srow) * 1024 + sx;
  const bf16* baseB1 = baseB0 + (size_t)128 * 1024;
  const int wvo = wv << 10;  // wave's linear 1 KiB LDS slice per half-tile

  // ---- fragment-read LDS byte addresses (swizzled) ----
  // Proper AS(3) offset: addrspacecast generic->LDS, then truncate.
  const uint32_t lds0 =
      (uint32_t)(uintptr_t)((__attribute__((address_space(3))) char*)smem_);
  const int fswz = col * 64 + ((quad ^ ((col >> 1) & 3)) << 4);
  const uint32_t abase = lds0 + (wm << 13) + fswz;          // A region
  const uint32_t bbase = lds0 + 16384 + (wn << 12) + fswz;  // B region

  floatx4 acc[8][4];
#pragma unroll
  for (int i = 0; i < 8; ++i)
#pragma unroll
    for (int j = 0; j < 4; ++j) acc[i][j] = (floatx4){0.f, 0.f, 0.f, 0.f};

  // ---- prologue: stage K-tiles 0..2 (12 loads), land tile 0 ----
#pragma unroll
  for (int pt = 0; pt < 3; ++pt) {
    char* sb = smem_ + (pt << 15) + wvo;
    gl_lds16(baseA0 + pt * 32, sb);
    gl_lds16(baseA1 + pt * 32, sb + 8192);
    gl_lds16(baseB0 + pt * 32, sb + 16384);
    gl_lds16(baseB1 + pt * 32, sb + 24576);
  }
  asm volatile("s_waitcnt vmcnt(8)" ::: "memory");
  WAITL(0);  // drain any prologue SMEM so loop lgkm counts are DS-pure
  __builtin_amdgcn_s_barrier();

#pragma unroll 1
  for (int t = 0; t < 32; ++t) {
    const uint32_t bufo = (uint32_t)((t & 3) << 15);
    const uint32_t ab = abase + bufo, bb = bbase + bufo;
    const int st = t + 3;
    char* sb = smem_ + ((st & 3) << 15) + wvo;

    // ------------- phase 0: issue B0..B3, A0..A3; stage A(t+3) ------------
    bf16x8 Bv0, Bv1, Bv2, Bv3, A0, A1, A2, A3;
    DSR(Bv0, bb, 0);
    DSR(Bv1, bb, 1024);
    DSR(Bv2, bb, 2048);
    DSR(Bv3, bb, 3072);
    DSR(A0, ab, 0);
    DSR(A1, ab, 1024);
    DSR(A2, ab, 2048);
    DSR(A3, ab, 3072);
    if (st < 32) {
      gl_lds16(baseA0 + st * 32, sb);
      gl_lds16(baseA1 + st * 32, sb + 8192);
    }
    __builtin_amdgcn_s_barrier();
    WAITL(3);  // B0..B3 + A0 landed
    SBAR();
    __builtin_amdgcn_s_setprio(1);
    acc[0][0] = mfma16(A0, Bv0, acc[0][0]);
    acc[0][1] = mfma16(A0, Bv1, acc[0][1]);
    acc[0][2] = mfma16(A0, Bv2, acc[0][2]);
    acc[0][3] = mfma16(A0, Bv3, acc[0][3]);
    SBAR();
    WAITL(2);  // A1
    SBAR();
    acc[1][0] = mfma16(A1, Bv0, acc[1][0]);
    acc[1][1] = mfma16(A1, Bv1, acc[1][1]);
    acc[1][2] = mfma16(A1, Bv2, acc[1][2]);
    acc[1][3] = mfma16(A1, Bv3, acc[1][3]);
    SBAR();
    WAITL(1);  // A2
    SBAR();
    acc[2][0] = mfma16(A2, Bv0, acc[2][0]);
    acc[2][1] = mfma16(A2, Bv1, acc[2][1]);
    acc[2][2] = mfma16(A2, Bv2, acc[2][2]);
    acc[2][3] = mfma16(A2, Bv3, acc[2][3]);
    SBAR();
    WAITL(0);  // A3
    SBAR();
    acc[3][0] = mfma16(A3, Bv0, acc[3][0]);
    acc[3][1] = mfma16(A3, Bv1, acc[3][1]);
    acc[3][2] = mfma16(A3, Bv2, acc[3][2]);
    acc[3][3] = mfma16(A3, Bv3, acc[3][3]);
    __builtin_amdgcn_s_setprio(0);
    SBAR();
    __builtin_amdgcn_s_barrier();

    // ------------- phase 1: issue A4..A7 (B in regs); stage B(t+3) --------
    bf16x8 A4, A5, A6, A7;
    DSR(A4, ab, 4096);
    DSR(A5, ab, 5120);
    DSR(A6, ab, 6144);
    DSR(A7, ab, 7168);
    if (st < 32) {
      gl_lds16(baseB0 + st * 32, sb + 16384);
      gl_lds16(baseB1 + st * 32, sb + 24576);
    }
    __builtin_amdgcn_s_barrier();
    WAITL(3);  // A4
    SBAR();
    __builtin_amdgcn_s_setprio(1);
    acc[4][0] = mfma16(A4, Bv0, acc[4][0]);
    acc[4][1] = mfma16(A4, Bv1, acc[4][1]);
    acc[4][2] = mfma16(A4, Bv2, acc[4][2]);
    acc[4][3] = mfma16(A4, Bv3, acc[4][3]);
    SBAR();
    WAITL(2);  // A5
    SBAR();
    acc[5][0] = mfma16(A5, Bv0, acc[5][0]);
    acc[5][1] = mfma16(A5, Bv1, acc[5][1]);
    acc[5][2] = mfma16(A5, Bv2, acc[5][2]);
    acc[5][3] = mfma16(A5, Bv3, acc[5][3]);
    SBAR();
    WAITL(1);  // A6
    SBAR();
    acc[6][0] = mfma16(A6, Bv0, acc[6][0]);
    acc[6][1] = mfma16(A6, Bv1, acc[6][1]);
    acc[6][2] = mfma16(A6, Bv2, acc[6][2]);
    acc[6][3] = mfma16(A6, Bv3, acc[6][3]);
    SBAR();
    WAITL(0);  // A7
    SBAR();
    acc[7][0] = mfma16(A7, Bv0, acc[7][0]);
    acc[7][1] = mfma16(A7, Bv1, acc[7][1]);
    acc[7][2] = mfma16(A7, Bv2, acc[7][2]);
    acc[7][3] = mfma16(A7, Bv3, acc[7][3]);
    __builtin_amdgcn_s_setprio(0);
    SBAR();
    // tile-boundary counted wait: tile t+1 landed, 2 tiles stay in flight
    if (t < 29)
      asm volatile("s_waitcnt vmcnt(8)" ::: "memory");
    else if (t == 29)
      asm volatile("s_waitcnt vmcnt(4)" ::: "memory");
    else if (t == 30)
      asm volatile("s_waitcnt vmcnt(0)" ::: "memory");
    __builtin_amdgcn_s_barrier();
  }

  // ---- epilogue: third is block-uniform (256 | 1024) ----
  const int third = by >> 2;
  const int wrow = wm * 128, wcol = wn * 64;
#pragma unroll
  for (int mb = 0; mb < 8; ++mb) {
    const int mgq = m0 + wrow + mb * 16 + quad * 4;  // 4 consecutive channels
    const int nn0 = mgq & 1023;
    const int h = nn0 >> 6, d0 = nn0 & 63;  // d0 4-aligned
    float bs[4];
#pragma unroll
    for (int r = 0; r < 4; ++r) bs[r] = bias[mgq + r];
#pragma unroll
    for (int nb = 0; nb < 4; ++nb) {
      const int tk = n0 + wcol + nb * 16 + col;  // token
      const int bb2 = tk >> 11, tt = tk & 2047;
      const size_t bh = (size_t)bb2 * H_ + h;
      float v[4];
#pragma unroll
      for (int r = 0; r < 4; ++r) v[r] = acc[mb][nb][r] + bs[r];
      if (third == 0) {
        bf16x4 y;
#pragma unroll
        for (int r = 0; r < 4; ++r) y[r] = (bf16)v[r];
        *(bf16x4*)&Qb[(bh * T_ + tt) * D_ + d0] = y;
      } else if (third == 1) {
        const int lane2 = (tt & 15) | (((d0 >> 3) & 3) << 4);
        const size_t idx =
            ((((bh * 64 + (tt >> 5)) * 2 + ((tt >> 4) & 1)) * 2 + (d0 >> 5)) * 64 +
             lane2) * 8 + (d0 & 7);
        bf16x4 y;
#pragma unroll
        for (int r = 0; r < 4; ++r) y[r] = (bf16)v[r];
        *(bf16x4*)&Kp[idx] = y;
      } else {
#pragma unroll
        for (int r = 0; r < 4; ++r) {
          const int d = d0 + r;
          const int lane2 = (d & 15) | (((tt >> 2) & 3) << 4);
          const size_t idx =
              (((bh * 64 + (tt >> 5)) * 4 + (d >> 4)) * 64 + lane2) * 8 +
              ((tt >> 4) & 1) * 4 + (tt & 3);
          Vp[idx] = (f16)v[r];
        }
      }
    }
  }
}

// ---------------- 128x128 bf16 MFMA GEMM, BK=64 (proj only now) ------------
// MODE 1 (proj): A=yb rows=tokens, bias by column, f32 row-major out.
template <int MODE>
__global__ __launch_bounds__(256) void gemm128(const bf16* __restrict__ A,
                                               const bf16* __restrict__ Bt,
                                               const float* __restrict__ bias,
                                               void* __restrict__ o0,
                                               bf16* __restrict__ o1,
                                               f16* __restrict__ o2,
                                               int M, int N, int K) {
  __shared__ __align__(16) bf16 As[2][128 * 32];
  __shared__ __align__(16) bf16 Bs[2][128 * 32];
  const int tid = threadIdx.x;
  const int m0 = blockIdx.y * 128, n0 = blockIdx.x * 128;
  const int lane = tid & 63, wv = tid >> 6;
  const int wm = (wv >> 1) * 64, wn = (wv & 1) * 64;
  const int col = lane & 15, quad = lane >> 4;

  floatx4 acc[4][4];
#pragma unroll
  for (int i = 0; i < 4; i++)
#pragma unroll
    for (int j = 0; j < 4; j++) acc[i][j] = (floatx4){0.f, 0.f, 0.f, 0.f};

  const int c0 = tid, c1 = tid + 256;
  const bf16* a0 = A + (size_t)(m0 + (c0 >> 2)) * K + (c0 & 3) * 8;
  const bf16* a1 = A + (size_t)(m0 + (c1 >> 2)) * K + (c1 & 3) * 8;
  const bf16* b0 = Bt + (size_t)(n0 + (c0 >> 2)) * K + (c0 & 3) * 8;
  const bf16* b1 = Bt + (size_t)(n0 + (c1 >> 2)) * K + (c1 & 3) * 8;

  for (int kt = 0; kt < K; kt += 64) {
#pragma unroll
    for (int hf = 0; hf < 2; hf++) {
      const int ko = kt + hf * 32;
      gl_lds16(a0 + ko, &As[hf][(wv * 64) * 8]);
      gl_lds16(a1 + ko, &As[hf][(wv * 64 + 256) * 8]);
      gl_lds16(b0 + ko, &Bs[hf][(wv * 64) * 8]);
      gl_lds16(b1 + ko, &Bs[hf][(wv * 64 + 256) * 8]);
    }
    __syncthreads();
#pragma unroll
    for (int hf = 0; hf < 2; hf++) {
      bf16x8 afr[4], bg[4];
#pragma unroll
      for (int mb = 0; mb < 4; mb++)
        afr[mb] = *(const bf16x8*)&As[hf][(wm + mb * 16 + col) * 32 + quad * 8];
#pragma unroll
      for (int nb = 0; nb < 4; nb++)
        bg[nb] = *(const bf16x8*)&Bs[hf][(wn + nb * 16 + col) * 32 + quad * 8];
#pragma unroll
      for (int mb = 0; mb < 4; mb++)
#pragma unroll
        for (int nb = 0; nb < 4; nb++)
          acc[mb][nb] = mfma16(afr[mb], bg[nb], acc[mb][nb]);
    }
    __syncthreads();
  }

#pragma unroll
  for (int mb = 0; mb < 4; mb++) {
    const int mgq = m0 + wm + mb * 16 + quad * 4;  // 4 consecutive rows
    {
#pragma unroll
      for (int nb = 0; nb < 4; nb++) {
        const int ng = n0 + wn + nb * 16 + col;
        const float bsc = bias[ng];
#pragma unroll
        for (int r = 0; r < 4; r++)
          ((float*)o0)[(size_t)(mgq + r) * N + ng] = acc[mb][nb][r] + bsc;
      }
    }
  }
}

// ---------------- flash attention: block = (bh, qtile); 4-way key split ----
// Q: [B,H,T,D] bf16; Kp/Vp: fragment-major (see gemm_qkv); Y: [B,T,C] bf16
__global__ __launch_bounds__(256, 4) void attn(const bf16* __restrict__ Q,
                                               const bf16* __restrict__ Kp,
                                               const f16* __restrict__ Vp,
                                               bf16* __restrict__ Y) {
  const int tid = threadIdx.x, lane = tid & 63, wv = tid >> 6;
  const int col = lane & 15, quad = lane >> 4;
  const int id = blockIdx.x;
  const int j = id >> 3;
  const int bh = ((j & 7) << 3) | (id & 7);
  const int qtile = 63 - (j >> 3);  // longest blocks dispatch first
  const int b = bh >> 4, h = bh & 15;
  const int qbase = qtile * 32;

  __shared__ __align__(16) floatx4 mbuf[3][8][64];  // 24 KB partial-O
  __shared__ float lbuf[3][2][64];                  // 1.5 KB partial-lsum

  bf16x8 qf[2][2];
#pragma unroll
  for (int mq = 0; mq < 2; mq++) {
    const bf16* qp = Q + ((size_t)bh * T_ + qbase + mq * 16 + col) * D_ + quad * 8;
    qf[mq][0] = *(const bf16x8*)qp;
    qf[mq][1] = *(const bf16x8*)(qp + 32);
  }

  floatx4 o[2][4];  // O^T: dim = sub*16 + quad*4 + r, qrow = col
  float lsum[2] = {0.f, 0.f};
#pragma unroll
  for (int mq = 0; mq < 2; mq++)
#pragma unroll
    for (int s = 0; s < 4; s++) o[mq][s] = (floatx4){0.f, 0.f, 0.f, 0.f};

  const float C1 = 0.18033688f;  // 0.125*log2(e)
  const float C2 = 11.541560f;   // 8*log2(e): p = exp2(s*C1 - C2), exact softmax

  const int nmine = (qtile >= wv) ? ((qtile - wv) >> 2) + 1 : 0;

  for (int i = 0; i < nmine; i++) {
    const int kt = wv + 4 * i;
    const bool masked = (kt == qtile);
    const bf16* kbase = Kp + ((size_t)bh * 64 + kt) * 2048 + lane * 8;
    const f16* vbase = Vp + ((size_t)bh * 64 + kt) * 2048 + lane * 8;
    bf16x8 ka[2][2];
    ka[0][0] = *(const bf16x8*)(kbase);
    ka[0][1] = *(const bf16x8*)(kbase + 512);
    ka[1][0] = *(const bf16x8*)(kbase + 1024);
    ka[1][1] = *(const bf16x8*)(kbase + 1536);
    f16x8 vv[4];
#pragma unroll
    for (int sub = 0; sub < 4; sub++) vv[sub] = *(const f16x8*)(vbase + sub * 512);

#pragma unroll
    for (int st = 0; st < 2; st++) {
#pragma unroll
      for (int mq = 0; mq < 2; mq++) {
        if (masked && mq == 0 && st == 1) continue;  // fully masked sub-tile
        floatx4 s = (floatx4){0.f, 0.f, 0.f, 0.f};
        s = mfma16(ka[st][0], qf[mq][0], s);
        s = mfma16(ka[st][1], qf[mq][1], s);
        f16x4 pf;
        float ps = 0.f;
        const bool diag = masked && (mq == st);
#pragma unroll
        for (int r = 0; r < 4; r++) {
          float p = exp2f(fmaf(s[r], C1, -C2));
          if (diag && (quad * 4 + r > col)) p = 0.f;
          ps += p;
          pf[r] = (f16)p;
        }
        lsum[mq] += ps;
#pragma unroll
        for (int sub = 0; sub < 4; sub++) {
          f16x4 va;
#pragma unroll
          for (int jj = 0; jj < 4; jj++) va[jj] = vv[sub][st * 4 + jj];
          o[mq][sub] = mfma_pv(va, pf, o[mq][sub]);
        }
      }
    }
  }

  if (wv != 0) {
#pragma unroll
    for (int mq = 0; mq < 2; mq++) {
#pragma unroll
      for (int sub = 0; sub < 4; sub++) mbuf[wv - 1][mq * 4 + sub][lane] = o[mq][sub];
      lbuf[wv - 1][mq][lane] = lsum[mq];
    }
  }
  __syncthreads();
  if (wv == 0) {
#pragma unroll
    for (int w = 0; w < 3; w++)
#pragma unroll
      for (int mq = 0; mq < 2; mq++) {
#pragma unroll
        for (int sub = 0; sub < 4; sub++) o[mq][sub] += mbuf[w][mq * 4 + sub][lane];
        lsum[mq] += lbuf[w][mq][lane];
      }
#pragma unroll
    for (int mq = 0; mq < 2; mq++) {
      lsum[mq] += __shfl_xor(lsum[mq], 16);
      lsum[mq] += __shfl_xor(lsum[mq], 32);
      const float rinv = 1.f / lsum[mq];
      const int qrow = qbase + mq * 16 + col;
#pragma unroll
      for (int sub = 0; sub < 4; sub++) {
        bf16x4 yv;
#pragma unroll
        for (int r = 0; r < 4; r++) yv[r] = (bf16)(o[mq][sub][r] * rinv);
        *(bf16x4*)&Y[((size_t)b * T_ + qrow) * C_ + h * 64 + sub * 16 + quad * 4] = yv;
      }
    }
  }
}

extern "C" void kernel_launch(void* const* d_in, const int* in_sizes, int n_in,
                              void* d_out, int out_size, void* d_ws, size_t ws_size,
                              hipStream_t stream) {
  (void)in_sizes; (void)n_in; (void)out_size; (void)ws_size;
  const float* x      = (const float*)d_in[0];  // [B*T, C]
  const float* w_qkv  = (const float*)d_in[1];  // [C, 3C]
  const float* b_qkv  = (const float*)d_in[2];  // [3C]
  const float* w_proj = (const float*)d_in[3];  // [C, C]
  const float* b_proj = (const float*)d_in[4];  // [C]

  char* ws = (char*)d_ws;
  bf16* wqkv_t  = (bf16*)(ws);                  // [3C, C]   6291456 B
  bf16* wproj_t = (bf16*)(ws + 6291456);        // [C, C]    2097152 B
  bf16* qb      = (bf16*)(ws + 8388608);        // [B,H,T,D] 16777216 B
  bf16* kbuf    = (bf16*)(ws + 25165824);       // K frag-major 16777216 B
  f16*  vtbuf   = (f16*)(ws + 41943040);        // V frag-major 16777216 B
  bf16* yb      = (bf16*)(ws + 58720256);       // [B*T, C]  16777216 B
  bf16* xb      = (bf16*)(ws + 58720256);       // aliases yb (dead before attn)

  // one-time opt-in for 128 KiB dynamic LDS (host-side, capture-safe)
  static bool attr_done = false;
  if (!attr_done) {
    hipFuncSetAttribute(reinterpret_cast<const void*>(gemm_qkv),
                        hipFuncAttributeMaxDynamicSharedMemorySize, 131072);
    attr_done = true;
  }

  cvt_bf16<<<8192, 256, 0, stream>>>(x, xb);
  transpose_f32<<<dim3(96, 32), 256, 0, stream>>>(w_qkv, wqkv_t, 1024, 3072);
  transpose_f32<<<dim3(32, 32), 256, 0, stream>>>(w_proj, wproj_t, 1024, 1024);
  // SWAPPED: A = wqkv_t (channels), Bt = xb (tokens)
  gemm_qkv<<<dim3(384), dim3(512), 131072, stream>>>(wqkv_t, xb, b_qkv, qb, kbuf,
                                                     vtbuf);
  attn<<<dim3(4096), 256, 0, stream>>>(qb, kbuf, vtbuf, yb);
  gemm128<1><<<dim3(8, 64), 256, 0, stream>>>(yb, wproj_t, b_proj, d_out, nullptr,
                                              nullptr, 8192, 1024, 1024);
}

// Round 4
// 257.811 us; speedup vs baseline: 1.0205x; 1.0205x over previous
//
#include <hip/hip_runtime.h>
#include <hip/hip_bf16.h>
#include <stdint.h>

// Problem constants: B=4, T=2048, C=1024, H=16, D=64. Inputs f32, output f32.
#define B_ 4
#define T_ 2048
#define C_ 1024
#define H_ 16
#define D_ 64

typedef __bf16 bf16;
typedef _Float16 f16;
typedef __attribute__((ext_vector_type(8))) __bf16 bf16x8;
typedef __attribute__((ext_vector_type(4))) __bf16 bf16x4;
typedef __attribute__((ext_vector_type(4))) _Float16 f16x4;
typedef __attribute__((ext_vector_type(8))) _Float16 f16x8;
typedef __attribute__((ext_vector_type(4))) float floatx4;

__device__ __forceinline__ floatx4 mfma16(bf16x8 a, bf16x8 b, floatx4 c) {
  return __builtin_amdgcn_mfma_f32_16x16x32_bf16(a, b, c, 0, 0, 0);
}
__device__ __forceinline__ floatx4 mfma_pv(f16x4 a, f16x4 b, floatx4 c) {
  return __builtin_amdgcn_mfma_f32_16x16x16f16(a, b, c, 0, 0, 0);
}

__device__ __forceinline__ void gl_lds16(const void* g, void* l) {
  __builtin_amdgcn_global_load_lds(
      (__attribute__((address_space(1))) uint32_t*)g,
      (__attribute__((address_space(3))) uint32_t*)l, 16, 0, 0);
}

// ---------------- f32 -> bf16 bulk convert ----------------
__global__ __launch_bounds__(256) void cvt_bf16(const float* __restrict__ in,
                                                bf16* __restrict__ out) {
  const size_t i = ((size_t)blockIdx.x * 256 + threadIdx.x) * 4;
  const floatx4 v = *(const floatx4*)(in + i);
  bf16x4 r;
#pragma unroll
  for (int j = 0; j < 4; j++) r[j] = (bf16)v[j];
  *(bf16x4*)(out + i) = r;
}

// ---------------- transpose: in[K][N] f32 -> out[N][K] bf16 ----------------
__global__ __launch_bounds__(256) void transpose_f32(const float* __restrict__ in,
                                                     bf16* __restrict__ out,
                                                     int K, int N) {
  __shared__ bf16 tile[32][33];
  const int n0 = blockIdx.x * 32, k0 = blockIdx.y * 32;
  const int r = threadIdx.x >> 5, c = threadIdx.x & 31;
#pragma unroll
  for (int i = 0; i < 4; i++)
    tile[r + i * 8][c] = (bf16)in[(size_t)(k0 + r + i * 8) * N + n0 + c];
  __syncthreads();
#pragma unroll
  for (int i = 0; i < 4; i++)
    out[(size_t)(n0 + r + i * 8) * K + k0 + c] = tile[c][r + i * 8];
}

// ---------------- 128x128 bf16 MFMA GEMM, BK=64 (two half-buffers) ----------
// C[M,N] = A[M,K] @ Bt[N,K]^T
// MODE 0 (QKV, SWAPPED orientation): A=wqkv_t rows=channels (M=3072),
//   Bt=xb rows=tokens (N=8192), bias indexed by CHANNEL (row).
//   Whole blocks map to one third (Q/K/V) -> uniform epilogue, packed stores.
//   Kp: [bh][kt(64)][st(2)][half(2)][lane(64)][8 bf16]
//   Vp: [bh][kt(64)][sub(4)][lane(64)][st0 f16x4|st1 f16x4]
// MODE 1 (proj): A=yb rows=tokens, bias by column, f32 row-major out.
// T1: XCD-chunked blockIdx swizzle (both grids % 8 == 0 -> bijective).
//   MODE 0: each XCD owns 8 consecutive token-panels (8x256KB xb = 2MB, L2-fit)
//   MODE 1: each XCD owns 8 consecutive row-panels of yb (2MB, L2-fit)
template <int MODE>
__global__ __launch_bounds__(256) void gemm128(const bf16* __restrict__ A,
                                               const bf16* __restrict__ Bt,
                                               const float* __restrict__ bias,
                                               void* __restrict__ o0,
                                               bf16* __restrict__ o1,
                                               f16* __restrict__ o2,
                                               int M, int N, int K) {
  __shared__ __align__(16) bf16 As[2][128 * 32];
  __shared__ __align__(16) bf16 Bs[2][128 * 32];
  const int tid = threadIdx.x;

  int bx, by;
  if (MODE == 0) {
    // grid (64, 24): 1536 blocks, flat id = x + y*64
    const int id = blockIdx.x + blockIdx.y * 64;
    const int xcd = id & 7, r = id >> 3;  // r in [0,192)
    bx = xcd * 8 + (r & 7);               // token-panel, [0,64)
    by = r >> 3;                          // channel-panel, [0,24)
  } else {
    // grid (8, 64): 512 blocks, flat id = x + y*8
    const int id = blockIdx.x + blockIdx.y * 8;
    const int xcd = id & 7, r = id >> 3;  // r in [0,64)
    bx = r & 7;                           // col-panel, [0,8)
    by = xcd * 8 + (r >> 3);              // row-panel, [0,64)
  }
  const int m0 = by * 128, n0 = bx * 128;

  const int lane = tid & 63, wv = tid >> 6;
  const int wm = (wv >> 1) * 64, wn = (wv & 1) * 64;
  const int col = lane & 15, quad = lane >> 4;

  floatx4 acc[4][4];
#pragma unroll
  for (int i = 0; i < 4; i++)
#pragma unroll
    for (int j = 0; j < 4; j++) acc[i][j] = (floatx4){0.f, 0.f, 0.f, 0.f};

  const int c0 = tid, c1 = tid + 256;
  const bf16* a0 = A + (size_t)(m0 + (c0 >> 2)) * K + (c0 & 3) * 8;
  const bf16* a1 = A + (size_t)(m0 + (c1 >> 2)) * K + (c1 & 3) * 8;
  const bf16* b0 = Bt + (size_t)(n0 + (c0 >> 2)) * K + (c0 & 3) * 8;
  const bf16* b1 = Bt + (size_t)(n0 + (c1 >> 2)) * K + (c1 & 3) * 8;

  for (int kt = 0; kt < K; kt += 64) {
#pragma unroll
    for (int hf = 0; hf < 2; hf++) {
      const int ko = kt + hf * 32;
      gl_lds16(a0 + ko, &As[hf][(wv * 64) * 8]);
      gl_lds16(a1 + ko, &As[hf][(wv * 64 + 256) * 8]);
      gl_lds16(b0 + ko, &Bs[hf][(wv * 64) * 8]);
      gl_lds16(b1 + ko, &Bs[hf][(wv * 64 + 256) * 8]);
    }
    __syncthreads();
#pragma unroll
    for (int hf = 0; hf < 2; hf++) {
      bf16x8 afr[4], bg[4];
#pragma unroll
      for (int mb = 0; mb < 4; mb++)
        afr[mb] = *(const bf16x8*)&As[hf][(wm + mb * 16 + col) * 32 + quad * 8];
#pragma unroll
      for (int nb = 0; nb < 4; nb++)
        bg[nb] = *(const bf16x8*)&Bs[hf][(wn + nb * 16 + col) * 32 + quad * 8];
#pragma unroll
      for (int mb = 0; mb < 4; mb++)
#pragma unroll
        for (int nb = 0; nb < 4; nb++)
          acc[mb][nb] = mfma16(afr[mb], bg[nb], acc[mb][nb]);
    }
    __syncthreads();
  }

#pragma unroll
  for (int mb = 0; mb < 4; mb++) {
    const int mgq = m0 + wm + mb * 16 + quad * 4;  // 4 consecutive rows
    if (MODE == 0) {
      // rows are channels; third/h/d block-uniform-ish, d0 4-aligned
      const int third = mgq >> 10;
      const int nn0 = mgq & 1023;
      const int h = nn0 >> 6, d0 = nn0 & 63;
      float bs[4];
#pragma unroll
      for (int r = 0; r < 4; r++) bs[r] = bias[mgq + r];
#pragma unroll
      for (int nb = 0; nb < 4; nb++) {
        const int t = n0 + wn + nb * 16 + col;  // token
        const int bb = t >> 11, tt = t & 2047;
        const size_t bh = (size_t)bb * H_ + h;
        float v[4];
#pragma unroll
        for (int r = 0; r < 4; r++) v[r] = acc[mb][nb][r] + bs[r];
        if (third == 0) {
          bf16x4 y;
#pragma unroll
          for (int r = 0; r < 4; r++) y[r] = (bf16)v[r];
          *(bf16x4*)&((bf16*)o0)[(bh * T_ + tt) * D_ + d0] = y;
        } else if (third == 1) {
          const int lane2 = (tt & 15) | (((d0 >> 3) & 3) << 4);
          const size_t idx =
              ((((bh * 64 + (tt >> 5)) * 2 + ((tt >> 4) & 1)) * 2 + (d0 >> 5)) * 64 +
               lane2) * 8 + (d0 & 7);
          bf16x4 y;
#pragma unroll
          for (int r = 0; r < 4; r++) y[r] = (bf16)v[r];
          *(bf16x4*)&o1[idx] = y;
        } else {
#pragma unroll
          for (int r = 0; r < 4; r++) {
            const int d = d0 + r;
            const int lane2 = (d & 15) | (((tt >> 2) & 3) << 4);
            const size_t idx =
                (((bh * 64 + (tt >> 5)) * 4 + (d >> 4)) * 64 + lane2) * 8 +
                ((tt >> 4) & 1) * 4 + (tt & 3);
            o2[idx] = (f16)v[r];
          }
        }
      }
    } else {
#pragma unroll
      for (int nb = 0; nb < 4; nb++) {
        const int ng = n0 + wn + nb * 16 + col;
        const float bsc = bias[ng];
#pragma unroll
        for (int r = 0; r < 4; r++)
          ((float*)o0)[(size_t)(mgq + r) * N + ng] = acc[mb][nb][r] + bsc;
      }
    }
  }
}

// ---------------- flash attention: block = (bh, qtile); 4-way key split ----
// Q: [B,H,T,D] bf16; Kp/Vp: fragment-major (see gemm128); Y: [B,T,C] bf16
// T5: setprio(1) around the MFMA-dense inner region (independent-block
// regime; measured-positive on attn-like kernels, null on lockstep GEMM).
__global__ __launch_bounds__(256, 4) void attn(const bf16* __restrict__ Q,
                                               const bf16* __restrict__ Kp,
                                               const f16* __restrict__ Vp,
                                               bf16* __restrict__ Y) {
  const int tid = threadIdx.x, lane = tid & 63, wv = tid >> 6;
  const int col = lane & 15, quad = lane >> 4;
  const int id = blockIdx.x;
  const int j = id >> 3;
  const int bh = ((j & 7) << 3) | (id & 7);
  const int qtile = 63 - (j >> 3);  // longest blocks dispatch first
  const int b = bh >> 4, h = bh & 15;
  const int qbase = qtile * 32;

  __shared__ __align__(16) floatx4 mbuf[3][8][64];  // 24 KB partial-O
  __shared__ float lbuf[3][2][64];                  // 1.5 KB partial-lsum

  bf16x8 qf[2][2];
#pragma unroll
  for (int mq = 0; mq < 2; mq++) {
    const bf16* qp = Q + ((size_t)bh * T_ + qbase + mq * 16 + col) * D_ + quad * 8;
    qf[mq][0] = *(const bf16x8*)qp;
    qf[mq][1] = *(const bf16x8*)(qp + 32);
  }

  floatx4 o[2][4];  // O^T: dim = sub*16 + quad*4 + r, qrow = col
  float lsum[2] = {0.f, 0.f};
#pragma unroll
  for (int mq = 0; mq < 2; mq++)
#pragma unroll
    for (int s = 0; s < 4; s++) o[mq][s] = (floatx4){0.f, 0.f, 0.f, 0.f};

  const float C1 = 0.18033688f;  // 0.125*log2(e)
  const float C2 = 11.541560f;   // 8*log2(e): p = exp2(s*C1 - C2), exact softmax

  const int nmine = (qtile >= wv) ? ((qtile - wv) >> 2) + 1 : 0;

  for (int i = 0; i < nmine; i++) {
    const int kt = wv + 4 * i;
    const bool masked = (kt == qtile);
    const bf16* kbase = Kp + ((size_t)bh * 64 + kt) * 2048 + lane * 8;
    const f16* vbase = Vp + ((size_t)bh * 64 + kt) * 2048 + lane * 8;
    bf16x8 ka[2][2];
    ka[0][0] = *(const bf16x8*)(kbase);
    ka[0][1] = *(const bf16x8*)(kbase + 512);
    ka[1][0] = *(const bf16x8*)(kbase + 1024);
    ka[1][1] = *(const bf16x8*)(kbase + 1536);
    f16x8 vv[4];
#pragma unroll
    for (int sub = 0; sub < 4; sub++) vv[sub] = *(const f16x8*)(vbase + sub * 512);

    __builtin_amdgcn_s_setprio(1);
#pragma unroll
    for (int st = 0; st < 2; st++) {
#pragma unroll
      for (int mq = 0; mq < 2; mq++) {
        if (masked && mq == 0 && st == 1) continue;  // fully masked sub-tile
        floatx4 s = (floatx4){0.f, 0.f, 0.f, 0.f};
        s = mfma16(ka[st][0], qf[mq][0], s);
        s = mfma16(ka[st][1], qf[mq][1], s);
        f16x4 pf;
        float ps = 0.f;
        const bool diag = masked && (mq == st);
#pragma unroll
        for (int r = 0; r < 4; r++) {
          float p = exp2f(fmaf(s[r], C1, -C2));
          if (diag && (quad * 4 + r > col)) p = 0.f;
          ps += p;
          pf[r] = (f16)p;
        }
        lsum[mq] += ps;
#pragma unroll
        for (int sub = 0; sub < 4; sub++) {
          f16x4 va;
#pragma unroll
          for (int jj = 0; jj < 4; jj++) va[jj] = vv[sub][st * 4 + jj];
          o[mq][sub] = mfma_pv(va, pf, o[mq][sub]);
        }
      }
    }
    __builtin_amdgcn_s_setprio(0);
  }

  if (wv != 0) {
#pragma unroll
    for (int mq = 0; mq < 2; mq++) {
#pragma unroll
      for (int sub = 0; sub < 4; sub++) mbuf[wv - 1][mq * 4 + sub][lane] = o[mq][sub];
      lbuf[wv - 1][mq][lane] = lsum[mq];
    }
  }
  __syncthreads();
  if (wv == 0) {
#pragma unroll
    for (int w = 0; w < 3; w++)
#pragma unroll
      for (int mq = 0; mq < 2; mq++) {
#pragma unroll
        for (int sub = 0; sub < 4; sub++) o[mq][sub] += mbuf[w][mq * 4 + sub][lane];
        lsum[mq] += lbuf[w][mq][lane];
      }
#pragma unroll
    for (int mq = 0; mq < 2; mq++) {
      lsum[mq] += __shfl_xor(lsum[mq], 16);
      lsum[mq] += __shfl_xor(lsum[mq], 32);
      const float rinv = 1.f / lsum[mq];
      const int qrow = qbase + mq * 16 + col;
#pragma unroll
      for (int sub = 0; sub < 4; sub++) {
        bf16x4 yv;
#pragma unroll
        for (int r = 0; r < 4; r++) yv[r] = (bf16)(o[mq][sub][r] * rinv);
        *(bf16x4*)&Y[((size_t)b * T_ + qrow) * C_ + h * 64 + sub * 16 + quad * 4] = yv;
      }
    }
  }
}

extern "C" void kernel_launch(void* const* d_in, const int* in_sizes, int n_in,
                              void* d_out, int out_size, void* d_ws, size_t ws_size,
                              hipStream_t stream) {
  (void)in_sizes; (void)n_in; (void)out_size; (void)ws_size;
  const float* x      = (const float*)d_in[0];  // [B*T, C]
  const float* w_qkv  = (const float*)d_in[1];  // [C, 3C]
  const float* b_qkv  = (const float*)d_in[2];  // [3C]
  const float* w_proj = (const float*)d_in[3];  // [C, C]
  const float* b_proj = (const float*)d_in[4];  // [C]

  char* ws = (char*)d_ws;
  bf16* wqkv_t  = (bf16*)(ws);                  // [3C, C]   6291456 B
  bf16* wproj_t = (bf16*)(ws + 6291456);        // [C, C]    2097152 B
  bf16* qb      = (bf16*)(ws + 8388608);        // [B,H,T,D] 16777216 B
  bf16* kbuf    = (bf16*)(ws + 25165824);       // K frag-major 16777216 B
  f16*  vtbuf   = (f16*)(ws + 41943040);        // V frag-major 16777216 B
  bf16* yb      = (bf16*)(ws + 58720256);       // [B*T, C]  16777216 B
  bf16* xb      = (bf16*)(ws + 58720256);       // aliases yb (dead before attn)

  cvt_bf16<<<8192, 256, 0, stream>>>(x, xb);
  transpose_f32<<<dim3(96, 32), 256, 0, stream>>>(w_qkv, wqkv_t, 1024, 3072);
  transpose_f32<<<dim3(32, 32), 256, 0, stream>>>(w_proj, wproj_t, 1024, 1024);
  // SWAPPED: A = wqkv_t (channels), Bt = xb (tokens)
  gemm128<0><<<dim3(64, 24), 256, 0, stream>>>(wqkv_t, xb, b_qkv, qb, kbuf, vtbuf,
                                               3072, 8192, 1024);
  attn<<<dim3(4096), 256, 0, stream>>>(qb, kbuf, vtbuf, yb);
  gemm128<1><<<dim3(8, 64), 256, 0, stream>>>(yb, wproj_t, b_proj, d_out, nullptr,
                                              nullptr, 8192, 1024, 1024);
}